// Round 4
// baseline (845.972 us; speedup 1.0000x reference)
//
#include <hip/hip_runtime.h>
#include <math.h>

typedef __attribute__((ext_vector_type(8))) short bf16x8;
typedef __attribute__((ext_vector_type(4))) float f32x4;

#define TPB 256
#define HROWS 50
#define DDIM 128

// ---------- bf16 split helpers ----------
static __device__ __forceinline__ unsigned short bf16_rne(float x) {
  union { float f; unsigned u; } v; v.f = x;
  return (unsigned short)((v.u + 0x7fffu + ((v.u >> 16) & 1u)) >> 16);
}
static __device__ __forceinline__ float bf16f(unsigned short h) {
  union { float f; unsigned u; } v; v.u = ((unsigned)h) << 16; return v.f;
}
static __device__ __forceinline__ void cvt_hilo(const float4 a, const float4 b,
                                                bf16x8& hi, bf16x8& lo) {
  unsigned short h;
  h = bf16_rne(a.x); hi[0] = (short)h; lo[0] = (short)bf16_rne(a.x - bf16f(h));
  h = bf16_rne(a.y); hi[1] = (short)h; lo[1] = (short)bf16_rne(a.y - bf16f(h));
  h = bf16_rne(a.z); hi[2] = (short)h; lo[2] = (short)bf16_rne(a.z - bf16f(h));
  h = bf16_rne(a.w); hi[3] = (short)h; lo[3] = (short)bf16_rne(a.w - bf16f(h));
  h = bf16_rne(b.x); hi[4] = (short)h; lo[4] = (short)bf16_rne(b.x - bf16f(h));
  h = bf16_rne(b.y); hi[5] = (short)h; lo[5] = (short)bf16_rne(b.y - bf16f(h));
  h = bf16_rne(b.z); hi[6] = (short)h; lo[6] = (short)bf16_rne(b.z - bf16f(h));
  h = bf16_rne(b.w); hi[7] = (short)h; lo[7] = (short)bf16_rne(b.w - bf16f(h));
}

static __device__ __forceinline__ float fast_tanh(float x) {
  float xc = fminf(fmaxf(x, -15.f), 15.f);
  float e  = __expf(2.f * xc);
  return (e - 1.f) / (e + 1.f);
}

// ws element layout (unsigned short elements):
//  fwT_hi [128][256] @ 0        fwT_lo [128][256] @ 32768
//  a1T_hi [64][128]  @ 65536    a1T_lo [64][128]  @ 73728
#define WS_FWT_LO 32768
#define WS_A1T_HI 65536
#define WS_A1T_LO 73728

// ---------- prep: coalesced 64x64 tile transpose + split-convert into ws ----------
// blocks 0..7: fusion_w [256][128] -> fwT[128][256]  (ti=bid>>1 k-tile, tj=bid&1 j-tile)
// blocks 8..9: attn1_w  [128][64]  -> a1T[64][128]   (ti=bid-8, tj=0)
__global__ void prep_w(const float* __restrict__ fw, const float* __restrict__ a1w,
                       unsigned short* __restrict__ ws) {
  __shared__ float tile[64][65];
  const int bid = blockIdx.x, t = threadIdx.x;
  const int ty = t >> 6, tx = t & 63;

  const float* src; int W, K, ti, tj; unsigned short *dh, *dl;
  if (bid < 8) { src = fw;  W = 128; K = 256; ti = bid >> 1; tj = bid & 1;
                 dh = ws;             dl = ws + WS_FWT_LO; }
  else         { src = a1w; W = 64;  K = 128; ti = bid - 8; tj = 0;
                 dh = ws + WS_A1T_HI; dl = ws + WS_A1T_LO; }

#pragma unroll
  for (int rr = 0; rr < 16; ++rr) {
    int r = ty * 16 + rr;                          // k within tile
    tile[r][tx] = src[(size_t)(ti * 64 + r) * W + tj * 64 + tx];
  }
  __syncthreads();
#pragma unroll
  for (int cc = 0; cc < 16; ++cc) {
    int c = ty * 16 + cc;                          // j within tile
    float x = tile[tx][c];                         // = src[ti*64+tx][tj*64+c]
    unsigned short hi = bf16_rne(x);
    unsigned short lo = bf16_rne(x - bf16f(hi));
    size_t o = (size_t)(tj * 64 + c) * K + ti * 64 + tx;
    dh[o] = hi;
    dl[o] = lo;
  }
}

// ---------- main fused kernel ----------
__global__ __launch_bounds__(TPB, 4)
void gnnrec_mfma(const int* __restrict__ user_idx,
                 const int* __restrict__ news_idx,
                 const int* __restrict__ history,
                 const float* __restrict__ gnn, int NGNN,
                 const float* __restrict__ user_table,
                 const float* __restrict__ news_table,
                 const float* __restrict__ fusion_b,
                 const float* __restrict__ ln_g,
                 const float* __restrict__ ln_b,
                 const float* __restrict__ attn1_b,
                 const float* __restrict__ attn2_w,
                 const float* __restrict__ attn2_b,
                 const float* __restrict__ ut_w,
                 const float* __restrict__ ut_b,
                 const float* __restrict__ nt_w,
                 const float* __restrict__ nt_b,
                 const unsigned short* __restrict__ ws,
                 float* __restrict__ out)
{
  __shared__ float hist_s[51][132];    // 26.9 KB (pad 132: phase-2 reads conflict-free)
  __shared__ float scratch[1024 + 384];// 5.5 KB
  __shared__ int   idx_s[64];
  __shared__ float score_s[HROWS];

  const int b    = blockIdx.x;
  const int t    = threadIdx.x;
  const int lane = t & 63;
  const int w    = t >> 6;             // wave 0..3
  const int c15  = lane & 15;
  const int g    = lane >> 4;          // k-group 0..3

  // ---------------- phase 0: indices ----------------
  if (t < HROWS)        idx_s[t] = history[b * HROWS + t];
  else if (t == HROWS)  idx_s[t] = news_idx[b];
  else if (t < 64)      idx_s[t] = 0;
  const int uidx = user_idx[b];
  __syncthreads();

  // ---------------- phase 1: fusion GEMM via MFMA, BARRIER-FREE ----------------
  // wave w owns output rows 16w..16w+15; lane (c15,g) supplies A[16w+c15][32kb+8g..+7].
  // B-frags read directly from pre-transposed ws (L1/L2-hot, identical across waves).
  const int arow = 16 * w + c15;
  const int aidx = idx_s[arow];
  const float* news_row = news_table + (size_t)aidx * DDIM;
  const bool   gnn_ok   = aidx < NGNN;
  const float* gnn_row  = gnn + (size_t)(gnn_ok ? aidx : 0) * DDIM;

  f32x4 acc[8];
#pragma unroll
  for (int ct = 0; ct < 8; ++ct) acc[ct] = (f32x4){0.f, 0.f, 0.f, 0.f};

  float4 xc0 = *(const float4*)(news_row + g * 8);
  float4 xc1 = *(const float4*)(news_row + g * 8 + 4);

  for (int kb = 0; kb < 8; ++kb) {
    // prefetch next A chunk (1-deep pipeline)
    float4 xn0 = make_float4(0.f, 0.f, 0.f, 0.f), xn1 = xn0;
    if (kb < 7) {
      int kn = kb + 1;
      if (kn < 4) {
        const float* p = news_row + kn * 32 + g * 8;
        xn0 = *(const float4*)p; xn1 = *(const float4*)(p + 4);
      } else if (gnn_ok) {
        const float* p = gnn_row + (kn - 4) * 32 + g * 8;
        xn0 = *(const float4*)p; xn1 = *(const float4*)(p + 4);
      }
    }
    bf16x8 aH, aL;
    cvt_hilo(xc0, xc1, aH, aL);
#pragma unroll
    for (int ct = 0; ct < 8; ++ct) {
      const unsigned short* pH = ws + (16 * ct + c15) * 256 + kb * 32 + g * 8;
      bf16x8 bH = *(const bf16x8*)pH;
      bf16x8 bL = *(const bf16x8*)(pH + WS_FWT_LO);
      acc[ct] = __builtin_amdgcn_mfma_f32_16x16x32_bf16(aH, bH, acc[ct], 0, 0, 0);
      acc[ct] = __builtin_amdgcn_mfma_f32_16x16x32_bf16(aH, bL, acc[ct], 0, 0, 0);
      acc[ct] = __builtin_amdgcn_mfma_f32_16x16x32_bf16(aL, bH, acc[ct], 0, 0, 0);
    }
    xc0 = xn0; xc1 = xn1;
  }

  // ---- phase 1 epilogue: +bias, LayerNorm (in-wave shfl), ReLU -> hist_s ----
  {
    float fbv[8], lgv[8], lbv[8];
#pragma unroll
    for (int ct = 0; ct < 8; ++ct) {
      fbv[ct] = fusion_b[16 * ct + c15];
      lgv[ct] = ln_g[16 * ct + c15];
      lbv[ct] = ln_b[16 * ct + c15];
    }
#pragma unroll
    for (int reg = 0; reg < 4; ++reg) {
      // C layout: row = 16w + 4g + reg, col = 16ct + c15
      float y[8];
      float s = 0.f, sq = 0.f;
#pragma unroll
      for (int ct = 0; ct < 8; ++ct) {
        y[ct] = acc[ct][reg] + fbv[ct];
        s += y[ct];
        sq += y[ct] * y[ct];
      }
#pragma unroll
      for (int off = 1; off <= 8; off <<= 1) {
        s  += __shfl_xor(s,  off);
        sq += __shfl_xor(sq, off);
      }
      float mean = s * (1.f / 128.f);
      float var  = sq * (1.f / 128.f) - mean * mean;
      float inv  = 1.f / sqrtf(var + 1e-5f);
      int row = 16 * w + 4 * g + reg;
      if (row < 51) {
#pragma unroll
        for (int ct = 0; ct < 8; ++ct) {
          float r = fmaxf((y[ct] - mean) * inv * lgv[ct] + lbv[ct], 0.f);
          hist_s[row][16 * ct + c15] = r;
        }
      }
    }
  }
  __syncthreads();   // hist rows are wave-local for phase 2, but phases 4+ read all rows

  // ---------------- phase 2: attention scores via MFMA (barrier-free) ----------------
  const unsigned short* a1T_hi = ws + WS_A1T_HI;
  const int hrow = (16 * w + c15) < 51 ? (16 * w + c15) : 50;

  bf16x8 aH2[4], aL2[4];
#pragma unroll
  for (int ks = 0; ks < 4; ++ks) {
    float4 h0 = *(const float4*)&hist_s[hrow][ks * 32 + g * 8];
    float4 h1 = *(const float4*)&hist_s[hrow][ks * 32 + g * 8 + 4];
    cvt_hilo(h0, h1, aH2[ks], aL2[ks]);
  }

  f32x4 acc2[4];
#pragma unroll
  for (int ct = 0; ct < 4; ++ct) acc2[ct] = (f32x4){0.f, 0.f, 0.f, 0.f};

#pragma unroll
  for (int ct = 0; ct < 4; ++ct) {
    const unsigned short* pH = a1T_hi + (16 * ct + c15) * 128 + g * 8;
#pragma unroll
    for (int ks = 0; ks < 4; ++ks) {
      bf16x8 bH = *(const bf16x8*)(pH + ks * 32);
      bf16x8 bL = *(const bf16x8*)(pH + 8192 + ks * 32);
      acc2[ct] = __builtin_amdgcn_mfma_f32_16x16x32_bf16(aH2[ks], bH, acc2[ct], 0, 0, 0);
      acc2[ct] = __builtin_amdgcn_mfma_f32_16x16x32_bf16(aH2[ks], bL, acc2[ct], 0, 0, 0);
      acc2[ct] = __builtin_amdgcn_mfma_f32_16x16x32_bf16(aL2[ks], bH, acc2[ct], 0, 0, 0);
    }
  }

  // ---- phase 2 epilogue: tanh, attn2 dot, in-wave reduce -> score_s ----
  {
    float a1bv[4], a2wv[4];
#pragma unroll
    for (int ct = 0; ct < 4; ++ct) {
      a1bv[ct] = attn1_b[16 * ct + c15];
      a2wv[ct] = attn2_w[16 * ct + c15];
    }
    const float a2b = attn2_b[0];
#pragma unroll
    for (int reg = 0; reg < 4; ++reg) {
      float p = 0.f;
#pragma unroll
      for (int ct = 0; ct < 4; ++ct)
        p += fast_tanh(acc2[ct][reg] + a1bv[ct]) * a2wv[ct];
#pragma unroll
      for (int off = 1; off <= 8; off <<= 1) p += __shfl_xor(p, off);
      int row = 16 * w + 4 * g + reg;
      if (row < HROWS && c15 == 0)
        score_s[row] = (idx_s[row] != 0) ? (p + a2b) : -1e9f;
    }
  }
  __syncthreads();

  // ---------------- phase 3: softmax over 50 (redundant per thread) ----------------
  float mx = -3.0e38f;
  for (int r = 0; r < HROWS; ++r) mx = fmaxf(mx, score_s[r]);
  __syncthreads();
  if (t < HROWS) score_s[t] = __expf(score_s[t] - mx);
  __syncthreads();
  float denom = 0.f;
  for (int r = 0; r < HROWS; ++r) denom += score_s[r];
  const float invd = 1.f / denom;

  // ---------------- phase 4: weighted sum -> hist_repr partials ----------------
  float* red = scratch;
  {
    int g8 = t >> 5, j4 = (t & 31) * 4;
    float p0 = 0.f, p1 = 0.f, p2 = 0.f, p3 = 0.f;
    for (int r = g8; r < HROWS; r += 8) {
      float wr = score_s[r] * invd;
      float4 hv = *(const float4*)&hist_s[r][j4];
      p0 = fmaf(wr, hv.x, p0);
      p1 = fmaf(wr, hv.y, p1);
      p2 = fmaf(wr, hv.z, p2);
      p3 = fmaf(wr, hv.w, p3);
    }
    *(float4*)&red[g8 * 128 + j4] = make_float4(p0, p1, p2, p3);
  }
  __syncthreads();

  // ---------------- phase 5: u = user_emb + hist_repr ----------------
  float* u_s  = scratch + 1024;
  float* ur_s = scratch + 1152;
  float* nr_s = scratch + 1280;
  if (t < 128) {
    float hr = 0.f;
#pragma unroll
    for (int q = 0; q < 8; ++q) hr += red[q * 128 + t];
    u_s[t] = user_table[(size_t)uidx * DDIM + t] + hr;
  }
  __syncthreads();

  // ---------------- phase 6: user/news transforms (128x128, fp32 VALU) ----------------
  {
    int path = t >> 7, j = t & 127;
    const float* Wm  = path ? nt_w : ut_w;
    const float* bm  = path ? nt_b : ut_b;
    const float* src = path ? &hist_s[50][0] : u_s;
    float a = 0.f;
#pragma unroll 8
    for (int k4 = 0; k4 < 32; ++k4) {
      float4 sv = *(const float4*)&src[k4 * 4];
      a = fmaf(sv.x, Wm[(size_t)(k4 * 4 + 0) * 128 + j], a);
      a = fmaf(sv.y, Wm[(size_t)(k4 * 4 + 1) * 128 + j], a);
      a = fmaf(sv.z, Wm[(size_t)(k4 * 4 + 2) * 128 + j], a);
      a = fmaf(sv.w, Wm[(size_t)(k4 * 4 + 3) * 128 + j], a);
    }
    a = fmaxf(a + bm[j], 0.f);
    (path ? nr_s : ur_s)[j] = a;
  }
  __syncthreads();

  // ---------------- phase 7: dot + sigmoid ----------------
  if (t < 64) {
    float p = ur_s[t] * nr_s[t] + ur_s[t + 64] * nr_s[t + 64];
    p += __shfl_xor(p, 1);
    p += __shfl_xor(p, 2);
    p += __shfl_xor(p, 4);
    p += __shfl_xor(p, 8);
    p += __shfl_xor(p, 16);
    p += __shfl_xor(p, 32);
    if (t == 0) out[b] = 1.f / (1.f + __expf(-p));
  }
}

extern "C" void kernel_launch(void* const* d_in, const int* in_sizes, int n_in,
                              void* d_out, int out_size, void* d_ws, size_t ws_size,
                              hipStream_t stream) {
  const int*   user_idx   = (const int*)d_in[0];
  const int*   news_idx   = (const int*)d_in[1];
  const int*   history    = (const int*)d_in[2];
  const float* gnn        = (const float*)d_in[3];
  const float* user_table = (const float*)d_in[4];
  const float* news_table = (const float*)d_in[5];
  const float* fusion_w   = (const float*)d_in[6];
  const float* fusion_b   = (const float*)d_in[7];
  const float* ln_g       = (const float*)d_in[8];
  const float* ln_b       = (const float*)d_in[9];
  const float* attn1_w    = (const float*)d_in[10];
  const float* attn1_b    = (const float*)d_in[11];
  const float* attn2_w    = (const float*)d_in[12];
  const float* attn2_b    = (const float*)d_in[13];
  const float* ut_w       = (const float*)d_in[14];
  const float* ut_b       = (const float*)d_in[15];
  const float* nt_w       = (const float*)d_in[16];
  const float* nt_b       = (const float*)d_in[17];

  const int B    = in_sizes[0];
  const int NGNN = in_sizes[3] / DDIM;
  float* out = (float*)d_out;
  unsigned short* ws = (unsigned short*)d_ws;

  prep_w<<<10, 256, 0, stream>>>(fusion_w, attn1_w, ws);

  gnnrec_mfma<<<B, TPB, 0, stream>>>(user_idx, news_idx, history, gnn, NGNN,
                                     user_table, news_table, fusion_b,
                                     ln_g, ln_b, attn1_b, attn2_w, attn2_b,
                                     ut_w, ut_b, nt_w, nt_b, ws, out);
}

// Round 6
// 539.730 us; speedup vs baseline: 1.5674x; 1.5674x over previous
//
#include <hip/hip_runtime.h>
#include <math.h>

typedef __attribute__((ext_vector_type(8))) short bf16x8;
typedef __attribute__((ext_vector_type(4))) float f32x4;
typedef unsigned int u32;

#define TPB 256
#define HROWS 50
#define DDIM 128

// ---- ws layout (bytes) ----
// fwTC: 8 chunk images of 16384B: [hi: 128col x 32k x 2B (8192)] [lo: 8192]
//       within hi: byte = col*64 + 2*k_within_chunk
// a1T : [64col][128k] hi then lo (col stride 256B, byte=2k)
// newsC/gnnC: per row 512B = [hi 128x2B][lo 128x2B]
#define WS_FWTC   0
#define WS_A1T_HI 131072
#define WS_A1T_LO 147456
#define WS_NEWSC  163840
#define WS_GNNC   (163840 + (size_t)100000*512)
#define WS_TAB_END (WS_GNNC + (size_t)80000*512)

static __device__ __forceinline__ u32 cvtpk(float a, float b) {
  u32 r;
  asm("v_cvt_pk_bf16_f32 %0, %1, %2" : "=v"(r) : "v"(a), "v"(b));
  return r;
}
static __device__ __forceinline__ float asf(u32 u) {
  union { u32 u; float f; } v; v.u = u; return v.f;
}
// 8 floats -> hi bf16x8 (HW RNE) + lo bf16x8 (residual)
static __device__ __forceinline__ void pack_hilo(const float* x, bf16x8& hi, bf16x8& lo) {
  union { u32 u[4]; bf16x8 v; } H, L;
#pragma unroll
  for (int i = 0; i < 4; ++i) H.u[i] = cvtpk(x[2 * i], x[2 * i + 1]);
#pragma unroll
  for (int i = 0; i < 4; ++i) {
    float r0 = x[2 * i]     - asf(H.u[i] << 16);
    float r1 = x[2 * i + 1] - asf(H.u[i] & 0xffff0000u);
    L.u[i] = cvtpk(r0, r1);
  }
  hi = H.v; lo = L.v;
}

static __device__ __forceinline__ float fast_tanh(float x) {
  float xc = fminf(fmaxf(x, -15.f), 15.f);
  float e  = __expf(2.f * xc);
  return (e - 1.f) / (e + 1.f);
}

// async global->LDS, 16B per lane; l = wave-uniform LDS base, g = per-lane src
static __device__ __forceinline__ void gload16(const void* g, void* l, int lane) {
#if __has_builtin(__builtin_amdgcn_global_load_lds)
  __builtin_amdgcn_global_load_lds(
      (const __attribute__((address_space(1))) u32*)g,
      (__attribute__((address_space(3))) u32*)l, 16, 0, 0);
#else
  *(int4*)((char*)l + lane * 16) = *(const int4*)g;
#endif
}

// ---------- prep 1: weights -> chunked/transposed bf16 hi/lo ----------
// blocks 0..7: fusion_w [256k][128j] -> chunk kb=bid  ; blocks 8..9: attn1_w [128k][64j]
__global__ void prep_w(const float* __restrict__ fw, const float* __restrict__ a1w,
                       char* __restrict__ wsb) {
  const int bid = blockIdx.x, t = threadIdx.x;
  if (bid < 8) {
    __shared__ float tile[32][129];
    const int kb = bid;
#pragma unroll
    for (int i = 0; i < 16; ++i) {
      int idx = i * 256 + t;                       // 0..4095
      tile[idx >> 7][idx & 127] = fw[(size_t)(32 * kb + (idx >> 7)) * 128 + (idx & 127)];
    }
    __syncthreads();
    const int col = t >> 1, half = t & 1;
    float x0[8], x1[8];
#pragma unroll
    for (int j = 0; j < 8; ++j) { x0[j] = tile[16 * half + j][col]; x1[j] = tile[16 * half + 8 + j][col]; }
    bf16x8 h0, l0, h1, l1;
    pack_hilo(x0, h0, l0); pack_hilo(x1, h1, l1);
    char* hb = wsb + WS_FWTC + kb * 16384 + col * 64 + half * 32;
    *(bf16x8*)hb = h0; *(bf16x8*)(hb + 16) = h1;
    *(bf16x8*)(hb + 8192) = l0; *(bf16x8*)(hb + 8192 + 16) = l1;
  } else {
    __shared__ float tile[64][65];
    const int ti = bid - 8;                        // k-half
#pragma unroll
    for (int i = 0; i < 16; ++i) {
      int idx = i * 256 + t;                       // 0..4095
      tile[idx >> 6][idx & 63] = a1w[(size_t)(64 * ti + (idx >> 6)) * 64 + (idx & 63)];
    }
    __syncthreads();
    const int col = t & 63, kq = t >> 6;           // kq 0..3
    float x0[8], x1[8];
#pragma unroll
    for (int j = 0; j < 8; ++j) { x0[j] = tile[kq * 16 + j][col]; x1[j] = tile[kq * 16 + 8 + j][col]; }
    bf16x8 h0, l0, h1, l1;
    pack_hilo(x0, h0, l0); pack_hilo(x1, h1, l1);
    size_t o = (size_t)col * 256 + ti * 128 + kq * 32;
    *(bf16x8*)(wsb + WS_A1T_HI + o) = h0; *(bf16x8*)(wsb + WS_A1T_HI + o + 16) = h1;
    *(bf16x8*)(wsb + WS_A1T_LO + o) = l0; *(bf16x8*)(wsb + WS_A1T_LO + o + 16) = l1;
  }
}

// ---------- prep 2: tables -> packed bf16 hi/lo rows ----------
__global__ void prep_tab(const float* __restrict__ news, const float* __restrict__ gnn,
                         int nNews, int nGnn, char* __restrict__ wsb) {
  int gidx = blockIdx.x * blockDim.x + threadIdx.x;
  int total = (nNews + nGnn) * 16;
  if (gidx >= total) return;
  const float* src; char* dst; int c;
  if (gidx < nNews * 16) {
    int row = gidx >> 4; c = gidx & 15;
    src = news + (size_t)row * 128 + c * 8;
    dst = wsb + WS_NEWSC + (size_t)row * 512;
  } else {
    int q = gidx - nNews * 16;
    int row = q >> 4; c = q & 15;
    src = gnn + (size_t)row * 128 + c * 8;
    dst = wsb + WS_GNNC + (size_t)row * 512;
  }
  float4 a = *(const float4*)src, b = *(const float4*)(src + 4);
  float x[8] = {a.x, a.y, a.z, a.w, b.x, b.y, b.z, b.w};
  bf16x8 hi, lo;
  pack_hilo(x, hi, lo);
  *(bf16x8*)(dst + c * 16) = hi;
  *(bf16x8*)(dst + 256 + c * 16) = lo;
}

// ---------- main fused kernel ----------
__global__ __launch_bounds__(TPB, 2)
void gnnrec_mfma(const int* __restrict__ user_idx,
                 const int* __restrict__ news_idx,
                 const int* __restrict__ history,
                 const float* __restrict__ gnnF, int NGNN,
                 const float* __restrict__ user_table,
                 const float* __restrict__ newsF,
                 const float* __restrict__ fusion_b,
                 const float* __restrict__ ln_g,
                 const float* __restrict__ ln_b,
                 const float* __restrict__ attn1_b,
                 const float* __restrict__ attn2_w,
                 const float* __restrict__ attn2_b,
                 const float* __restrict__ ut_w,
                 const float* __restrict__ ut_b,
                 const float* __restrict__ nt_w,
                 const float* __restrict__ nt_b,
                 const char* __restrict__ wsb, int pre,
                 float* __restrict__ out)
{
  // LDS union: [0..32768) = fw dbuf (phase1) -> a1T swizzled (phase2) -> scratch (ph4+)
  //            [32768..59696) = hist_s[51][132] f32
  __shared__ __attribute__((aligned(16))) char Lb[59712];
  __shared__ int   idx_s[64];
  __shared__ float score_s[HROWS];
  __shared__ float statS[64][2], statQ[64][2];
  float (*hist_s)[132] = (float(*)[132])(Lb + 32768);

  const int b    = blockIdx.x;
  const int t    = threadIdx.x;
  const int lane = t & 63;
  const int w    = t >> 6;            // wave 0..3
  const int c15  = lane & 15;
  const int g    = lane >> 4;         // k-group 0..3
  const int wr   = w >> 1, wc = w & 1;

  // ---------------- phase 0: indices + first stage ----------------
  if (t < HROWS)        idx_s[t] = history[b * HROWS + t];
  else if (t == HROWS)  idx_s[t] = news_idx[b];
  else if (t < 64)      idx_s[t] = 0;
  const int uidx = user_idx[b];
  {  // stage chunk 0 -> buf0 (issued before barrier; barrier drains vmcnt)
    const char* s = wsb + WS_FWTC + w * 4096 + lane * 16;
    char* d = Lb + w * 4096;
#pragma unroll
    for (int i = 0; i < 4; ++i) gload16(s + i * 1024, d + i * 1024, lane);
  }
  __syncthreads();

  // per-lane A-row info (2 row-tiles)
  bool gok[2];
  const char *nrowC[2], *growC[2];
  const float *nrowF[2], *growF[2];
#pragma unroll
  for (int rt = 0; rt < 2; ++rt) {
    int r = 32 * wr + 16 * rt + c15;
    int idx = idx_s[r];
    gok[rt] = idx < NGNN;
    nrowC[rt] = wsb + WS_NEWSC + (size_t)idx * 512;
    growC[rt] = wsb + WS_GNNC + (size_t)(gok[rt] ? idx : 0) * 512;
    nrowF[rt] = newsF + (size_t)idx * DDIM;
    growF[rt] = gnnF + (size_t)(gok[rt] ? idx : 0) * DDIM;
  }

  auto loadA = [&](int kb, bf16x8* aH, bf16x8* aL) {
#pragma unroll
    for (int rt = 0; rt < 2; ++rt) {
      if (pre) {
        if (kb < 4) {
          const char* p = nrowC[rt] + kb * 64 + g * 16;
          aH[rt] = *(const bf16x8*)p;
          aL[rt] = *(const bf16x8*)(p + 256);
        } else if (gok[rt]) {
          const char* p = growC[rt] + (kb - 4) * 64 + g * 16;
          aH[rt] = *(const bf16x8*)p;
          aL[rt] = *(const bf16x8*)(p + 256);
        } else {
          bf16x8 z = {0, 0, 0, 0, 0, 0, 0, 0};
          aH[rt] = z; aL[rt] = z;
        }
      } else {
        float x[8];
        bool have = true;
        const float* p = nullptr;
        if (kb < 4) p = nrowF[rt] + kb * 32 + g * 8;
        else if (gok[rt]) p = growF[rt] + (kb - 4) * 32 + g * 8;
        else have = false;
        if (have) {
          float4 a = *(const float4*)p, bb = *(const float4*)(p + 4);
          x[0]=a.x; x[1]=a.y; x[2]=a.z; x[3]=a.w; x[4]=bb.x; x[5]=bb.y; x[6]=bb.z; x[7]=bb.w;
        } else {
#pragma unroll
          for (int j = 0; j < 8; ++j) x[j] = 0.f;
        }
        pack_hilo(x, aH[rt], aL[rt]);
      }
    }
  };

  // ---------------- phase 1: fusion GEMM (64x256 @ 256x128), 1 barrier/chunk ----------------
  f32x4 acc[2][4];
#pragma unroll
  for (int rt = 0; rt < 2; ++rt)
#pragma unroll
    for (int ct = 0; ct < 4; ++ct) acc[rt][ct] = (f32x4){0.f, 0.f, 0.f, 0.f};

  bf16x8 aHc[2], aLc[2], aHn[2], aLn[2];
  loadA(0, aHc, aLc);

#pragma unroll
  for (int kb = 0; kb < 8; ++kb) {
    const int cur = kb & 1;
    if (kb < 7) {
      const char* s = wsb + WS_FWTC + (kb + 1) * 16384 + w * 4096 + lane * 16;
      char* d = Lb + (cur ^ 1) * 16384 + w * 4096;
#pragma unroll
      for (int i = 0; i < 4; ++i) gload16(s + i * 1024, d + i * 1024, lane);
      loadA(kb + 1, aHn, aLn);
    }
#pragma unroll
    for (int ct = 0; ct < 4; ++ct) {
      const char* pb = Lb + cur * 16384 + (64 * wc + 16 * ct + c15) * 64 + g * 16;
      bf16x8 bH = *(const bf16x8*)pb;
      bf16x8 bL = *(const bf16x8*)(pb + 8192);
#pragma unroll
      for (int rt = 0; rt < 2; ++rt) {
        acc[rt][ct] = __builtin_amdgcn_mfma_f32_16x16x32_bf16(aHc[rt], bH, acc[rt][ct], 0, 0, 0);
        acc[rt][ct] = __builtin_amdgcn_mfma_f32_16x16x32_bf16(aHc[rt], bL, acc[rt][ct], 0, 0, 0);
        acc[rt][ct] = __builtin_amdgcn_mfma_f32_16x16x32_bf16(aLc[rt], bH, acc[rt][ct], 0, 0, 0);
      }
    }
    __syncthreads();
    if (kb < 7) { aHc[0] = aHn[0]; aHc[1] = aHn[1]; aLc[0] = aLn[0]; aLc[1] = aLn[1]; }
  }

  // ---- phase 1 epilogue: bias, cross-wave LN stats, ReLU -> hist_s ----
  float fb[4], lg[4], lb[4];
#pragma unroll
  for (int ct = 0; ct < 4; ++ct) {
    int col = 64 * wc + 16 * ct + c15;
    fb[ct] = fusion_b[col]; lg[ct] = ln_g[col]; lb[ct] = ln_b[col];
  }
  float ys[2][4][4];                    // [rt][reg][ct]
#pragma unroll
  for (int rt = 0; rt < 2; ++rt)
#pragma unroll
    for (int reg = 0; reg < 4; ++reg) {
      float s = 0.f, sq = 0.f;
#pragma unroll
      for (int ct = 0; ct < 4; ++ct) {
        float y = acc[rt][ct][reg] + fb[ct];
        ys[rt][reg][ct] = y;
        s += y; sq += y * y;
      }
#pragma unroll
      for (int off = 1; off <= 8; off <<= 1) {
        s  += __shfl_xor(s,  off);
        sq += __shfl_xor(sq, off);
      }
      if (c15 == 0) {
        int row = 32 * wr + 16 * rt + 4 * g + reg;
        statS[row][wc] = s; statQ[row][wc] = sq;
      }
    }
  __syncthreads();                       // stats published; all buf reads done

  // a1T stage -> Lb[0..32768) XOR-swizzled (overlaps LN finish)
  {
    const int col = t >> 2, q = t & 3;
    const char* sh = wsb + WS_A1T_HI + (size_t)col * 256 + q * 64;
    const char* sl = wsb + WS_A1T_LO + (size_t)col * 256 + q * 64;
    const int swz = (col & 15) << 4;
#pragma unroll
    for (int i = 0; i < 4; ++i) {
      int koff = q * 64 + i * 16;
      *(int4*)(Lb + ((col * 512 + koff) ^ swz))       = *(const int4*)(sh + i * 16);
      *(int4*)(Lb + ((col * 512 + 256 + koff) ^ swz)) = *(const int4*)(sl + i * 16);
    }
  }
  // LN finish + hist writes (disjoint from a1T region)
#pragma unroll
  for (int rt = 0; rt < 2; ++rt)
#pragma unroll
    for (int reg = 0; reg < 4; ++reg) {
      int row = 32 * wr + 16 * rt + 4 * g + reg;
      float S = statS[row][0] + statS[row][1];
      float Q = statQ[row][0] + statQ[row][1];
      float mean = S * (1.f / 128.f);
      float var  = Q * (1.f / 128.f) - mean * mean;
      float inv  = 1.f / sqrtf(var + 1e-5f);
      if (row < 51) {
#pragma unroll
        for (int ct = 0; ct < 4; ++ct) {
          float r = fmaxf((ys[rt][reg][ct] - mean) * inv * lg[ct] + lb[ct], 0.f);
          hist_s[row][64 * wc + 16 * ct + c15] = r;
        }
      }
    }
  __syncthreads();                       // hist + a1T visible

  // ---------------- phase 2: attention scores (rows 16w+c15, cols 0..63) ----------------
  const int hrow = (16 * w + c15) < 51 ? (16 * w + c15) : 50;
  bf16x8 aH2[4], aL2[4];
#pragma unroll
  for (int ks = 0; ks < 4; ++ks) {
    float4 h0 = *(const float4*)&hist_s[hrow][ks * 32 + g * 8];
    float4 h1 = *(const float4*)&hist_s[hrow][ks * 32 + g * 8 + 4];
    float x[8] = {h0.x, h0.y, h0.z, h0.w, h1.x, h1.y, h1.z, h1.w};
    pack_hilo(x, aH2[ks], aL2[ks]);
  }
  f32x4 acc2[4];
#pragma unroll
  for (int ct = 0; ct < 4; ++ct) acc2[ct] = (f32x4){0.f, 0.f, 0.f, 0.f};
#pragma unroll
  for (int ct = 0; ct < 4; ++ct) {
    const int colb = 16 * ct + c15;
    const int swz = (colb & 15) << 4;
#pragma unroll
    for (int ks = 0; ks < 4; ++ks) {
      const int off = ks * 64 + g * 16;
      bf16x8 bH = *(const bf16x8*)(Lb + ((colb * 512 + off) ^ swz));
      bf16x8 bL = *(const bf16x8*)(Lb + ((colb * 512 + 256 + off) ^ swz));
      acc2[ct] = __builtin_amdgcn_mfma_f32_16x16x32_bf16(aH2[ks], bH, acc2[ct], 0, 0, 0);
      acc2[ct] = __builtin_amdgcn_mfma_f32_16x16x32_bf16(aH2[ks], bL, acc2[ct], 0, 0, 0);
      acc2[ct] = __builtin_amdgcn_mfma_f32_16x16x32_bf16(aL2[ks], bH, acc2[ct], 0, 0, 0);
    }
  }
  {
    float a1bv[4], a2wv[4];
#pragma unroll
    for (int ct = 0; ct < 4; ++ct) {
      a1bv[ct] = attn1_b[16 * ct + c15];
      a2wv[ct] = attn2_w[16 * ct + c15];
    }
    const float a2b = attn2_b[0];
#pragma unroll
    for (int reg = 0; reg < 4; ++reg) {
      float p = 0.f;
#pragma unroll
      for (int ct = 0; ct < 4; ++ct)
        p += fast_tanh(acc2[ct][reg] + a1bv[ct]) * a2wv[ct];
#pragma unroll
      for (int off = 1; off <= 8; off <<= 1) p += __shfl_xor(p, off);
      int row = 16 * w + 4 * g + reg;
      if (row < HROWS && c15 == 0)
        score_s[row] = (idx_s[row] != 0) ? (p + a2b) : -1e9f;
    }
  }
  __syncthreads();

  // ---------------- phase 3: softmax over 50 ----------------
  float mx = -3.0e38f;
  for (int r = 0; r < HROWS; ++r) mx = fmaxf(mx, score_s[r]);
  __syncthreads();
  if (t < HROWS) score_s[t] = __expf(score_s[t] - mx);
  __syncthreads();
  float denom = 0.f;
  for (int r = 0; r < HROWS; ++r) denom += score_s[r];
  const float invd = 1.f / denom;

  // ---------------- phase 4: weighted sum -> hist_repr partials ----------------
  float* red = (float*)Lb;               // a1T region dead now
  {
    int g8 = t >> 5, j4 = (t & 31) * 4;
    float p0 = 0.f, p1 = 0.f, p2 = 0.f, p3 = 0.f;
    for (int r = g8; r < HROWS; r += 8) {
      float wrr = score_s[r] * invd;
      float4 hv = *(const float4*)&hist_s[r][j4];
      p0 = fmaf(wrr, hv.x, p0);
      p1 = fmaf(wrr, hv.y, p1);
      p2 = fmaf(wrr, hv.z, p2);
      p3 = fmaf(wrr, hv.w, p3);
    }
    *(float4*)&red[g8 * 128 + j4] = make_float4(p0, p1, p2, p3);
  }
  __syncthreads();

  // ---------------- phase 5: u = user_emb + hist_repr ----------------
  float* u_s  = red + 1024;
  float* ur_s = red + 1152;
  float* nr_s = red + 1280;
  if (t < 128) {
    float hr = 0.f;
#pragma unroll
    for (int q = 0; q < 8; ++q) hr += red[q * 128 + t];
    u_s[t] = user_table[(size_t)uidx * DDIM + t] + hr;
  }
  __syncthreads();

  // ---------------- phase 6: user/news transforms (128x128, fp32 VALU) ----------------
  {
    int path = t >> 7, j = t & 127;
    const float* Wm  = path ? nt_w : ut_w;
    const float* bm  = path ? nt_b : ut_b;
    const float* src = path ? &hist_s[50][0] : u_s;
    float a = 0.f;
#pragma unroll 8
    for (int k4 = 0; k4 < 32; ++k4) {
      float4 sv = *(const float4*)&src[k4 * 4];
      a = fmaf(sv.x, Wm[(size_t)(k4 * 4 + 0) * 128 + j], a);
      a = fmaf(sv.y, Wm[(size_t)(k4 * 4 + 1) * 128 + j], a);
      a = fmaf(sv.z, Wm[(size_t)(k4 * 4 + 2) * 128 + j], a);
      a = fmaf(sv.w, Wm[(size_t)(k4 * 4 + 3) * 128 + j], a);
    }
    a = fmaxf(a + bm[j], 0.f);
    (path ? nr_s : ur_s)[j] = a;
  }
  __syncthreads();

  // ---------------- phase 7: dot + sigmoid ----------------
  if (t < 64) {
    float p = ur_s[t] * nr_s[t] + ur_s[t + 64] * nr_s[t + 64];
    p += __shfl_xor(p, 1);
    p += __shfl_xor(p, 2);
    p += __shfl_xor(p, 4);
    p += __shfl_xor(p, 8);
    p += __shfl_xor(p, 16);
    p += __shfl_xor(p, 32);
    if (t == 0) out[b] = 1.f / (1.f + __expf(-p));
  }
}

extern "C" void kernel_launch(void* const* d_in, const int* in_sizes, int n_in,
                              void* d_out, int out_size, void* d_ws, size_t ws_size,
                              hipStream_t stream) {
  const int*   user_idx   = (const int*)d_in[0];
  const int*   news_idx   = (const int*)d_in[1];
  const int*   history    = (const int*)d_in[2];
  const float* gnn        = (const float*)d_in[3];
  const float* user_table = (const float*)d_in[4];
  const float* news_table = (const float*)d_in[5];
  const float* fusion_w   = (const float*)d_in[6];
  const float* fusion_b   = (const float*)d_in[7];
  const float* ln_g       = (const float*)d_in[8];
  const float* ln_b       = (const float*)d_in[9];
  const float* attn1_w    = (const float*)d_in[10];
  const float* attn1_b    = (const float*)d_in[11];
  const float* attn2_w    = (const float*)d_in[12];
  const float* attn2_b    = (const float*)d_in[13];
  const float* ut_w       = (const float*)d_in[14];
  const float* ut_b       = (const float*)d_in[15];
  const float* nt_w       = (const float*)d_in[16];
  const float* nt_b       = (const float*)d_in[17];

  const int B     = in_sizes[0];
  const int NGNN  = in_sizes[3] / DDIM;
  const int NNEWS = in_sizes[5] / DDIM;
  float* out = (float*)d_out;
  char* wsb = (char*)d_ws;
  const int pre = (ws_size >= WS_TAB_END) ? 1 : 0;

  prep_w<<<10, 256, 0, stream>>>(fusion_w, attn1_w, wsb);
  if (pre) {
    int total = (NNEWS + NGNN) * 16;
    prep_tab<<<(total + 255) / 256, 256, 0, stream>>>(news_table, gnn, NNEWS, NGNN, wsb);
  }
  gnnrec_mfma<<<B, TPB, 0, stream>>>(user_idx, news_idx, history, gnn, NGNN,
                                     user_table, news_table, fusion_b,
                                     ln_g, ln_b, attn1_b, attn2_w, attn2_b,
                                     ut_w, ut_b, nt_w, nt_b, wsb, pre, out);
}